// Round 6
// baseline (363.551 us; speedup 1.0000x reference)
//
#include <hip/hip_runtime.h>

// HeteroGraphSage on MI355X — round 16: single-pass scatter (no 8x partition
// replication). R15 killed the L2-thrash theory: WRITE_SIZE ~= 1M x 64B means
// record stores NEVER coalesce, partitioned or not — so 8x replication was
// pure read-side cost (~48MB extra HBM + 8x blocks with 7/8 lanes idle).
// Atomic count is identical either way (1M); this round tests whether
// device atomics are XCD-agnostic (memory-side) by dropping the filter.
// If setup >= 80us: line-migration atomics confirmed -> revert to 8x forever.
// Pipeline: memset(cursor) -> [prep|cvt|scatter] -> gather -> acct.
//   neigh64[a] = sum_e w_e * x_m[src_e] ; sumw[a] = sum_e w_e
//   h_a = relu( Wcomb @ [x_a | neigh64] + sumw*vbr + beff )
//   out = sigmoid(Wo . h_a + bo)
// Lessons: R7 — edge phases need huge TLP; R8/R9 — cursor contention/XCD
// partition (mechanism now under test); R10 — harness fill ~60us fixed;
// R11 — capacity-32 buckets == exact CSR (Poisson(5)); R12 — ILP-batch 8
// edges/thread; R13 — scatter not read-latency bound; R14 — acct 512-thr
// occupancy fix; R15 — NT streaming neutral, store amplification structural.

typedef __attribute__((ext_vector_type(8))) short short8;
typedef __attribute__((ext_vector_type(4))) float f32x4;

#define CAP 32   // bucket capacity (max observed degree ~19; P(>=32) ~ 1e-15/row)

__device__ inline unsigned short f32_bf16(float f) {
  unsigned int u = __float_as_uint(f);
  u += 0x7FFF + ((u >> 16) & 1);   // round-to-nearest-even
  return (unsigned short)(u >> 16);
}
__device__ inline unsigned int pk_bf16(float a, float b) {
  return (unsigned int)f32_bf16(a) | ((unsigned int)f32_bf16(b) << 16);
}

// ---- merged front-end: [prep | cvt_xm | scatter] by blockIdx range ---------
// record: [wq:15b << 17 | src:17b]; w in [0,1) -> q=w*32768, err <= 3e-5.
__global__ __launch_bounds__(256) void setup_kernel(
    const float* __restrict__ xm, unsigned int* __restrict__ xmbf, int nq,
    const int* __restrict__ src, const int* __restrict__ dst,
    const float* __restrict__ w, int* __restrict__ cursor,
    unsigned int* __restrict__ edges, int E,
    const float* __restrict__ Wp_a, const float* __restrict__ bp_a,
    const float* __restrict__ Wr_ma, const float* __restrict__ br_ma,
    const float* __restrict__ Wc_a, const float* __restrict__ bc_a,
    unsigned short* __restrict__ Wcomb, float* __restrict__ beff,
    float* __restrict__ vbr, int nb_cvt) {
  __shared__ float wc_s[256];
  int b = blockIdx.x;
  int t = threadIdx.x;
  if (b < 128) {
    // ---- prep: fold Wc_a @ [Wp_a ; Wr_ma] into Wcomb[128][192] bf16 -------
    int col = b;
    wc_s[t] = Wc_a[col * 256 + t];
    __syncthreads();
    int wave = t >> 6, lane = t & 63;
    if (wave < 2) {
      int k = t;   // 0..127
      float acc = 0.f;
#pragma unroll
      for (int j = 0; j < 128; j += 4) {
        float a0 = Wp_a[(j + 0) * 128 + k];
        float a1 = Wp_a[(j + 1) * 128 + k];
        float a2 = Wp_a[(j + 2) * 128 + k];
        float a3 = Wp_a[(j + 3) * 128 + k];
        acc += wc_s[j] * a0 + wc_s[j + 1] * a1 + wc_s[j + 2] * a2 + wc_s[j + 3] * a3;
      }
      Wcomb[col * 192 + k] = f32_bf16(acc);
    } else if (wave == 2) {
      int kk = lane;   // 0..63
      float acc = 0.f;
#pragma unroll
      for (int j = 0; j < 128; j += 4) {
        float a0 = Wr_ma[(j + 0) * 64 + kk];
        float a1 = Wr_ma[(j + 1) * 64 + kk];
        float a2 = Wr_ma[(j + 2) * 64 + kk];
        float a3 = Wr_ma[(j + 3) * 64 + kk];
        acc += wc_s[128 + j] * a0 + wc_s[129 + j] * a1 + wc_s[130 + j] * a2 + wc_s[131 + j] * a3;
      }
      Wcomb[col * 192 + 128 + kk] = f32_bf16(acc);
    } else {
      float v1 = wc_s[lane] * bp_a[lane] + wc_s[lane + 64] * bp_a[lane + 64];
      float v2 = wc_s[128 + lane] * br_ma[lane] + wc_s[192 + lane] * br_ma[lane + 64];
#pragma unroll
      for (int m = 1; m <= 32; m <<= 1) {
        v1 += __shfl_xor(v1, m, 64);
        v2 += __shfl_xor(v2, m, 64);
      }
      if (lane == 0) { beff[col] = v1 + bc_a[col]; vbr[col] = v2; }
    }
    return;
  }
  b -= 128;
  if (b < nb_cvt) {
    // ---- cvt: x_merchant f32 -> packed bf16 pairs, float4-vectorized ------
    int i = b * 256 + t;
    if (i < nq) {
      float4 v = ((const float4*)xm)[i];
      ((uint2*)xmbf)[i] = make_uint2(pk_bf16(v.x, v.y), pk_bf16(v.z, v.w));
    }
    return;
  }
  b -= nb_cvt;
  // ---- scatter: single-pass, 8 edges/thread, commit all ------------------
  int e0 = b * 2048 + t * 8;
  if (e0 >= E) return;
  if (e0 + 8 <= E) {
    int4 da = ((const int4*)(dst + e0))[0];
    int4 db = ((const int4*)(dst + e0))[1];
    int4 sa = ((const int4*)(src + e0))[0];
    int4 sb = ((const int4*)(src + e0))[1];
    float4 wa = ((const float4*)(w + e0))[0];
    float4 wb = ((const float4*)(w + e0))[1];
    int dv[8] = {da.x, da.y, da.z, da.w, db.x, db.y, db.z, db.w};
    int sv[8] = {sa.x, sa.y, sa.z, sa.w, sb.x, sb.y, sb.z, sb.w};
    float wv[8] = {wa.x, wa.y, wa.z, wa.w, wb.x, wb.y, wb.z, wb.w};
    unsigned int rec[8];
    int idx[8];
#pragma unroll
    for (int k = 0; k < 8; ++k) {
      unsigned int q = (unsigned int)fminf(wv[k] * 32768.0f, 32767.0f);
      rec[k] = (unsigned int)sv[k] | (q << 17);
    }
#pragma unroll
    for (int k = 0; k < 8; ++k) idx[k] = atomicAdd(&cursor[dv[k]], 1);
#pragma unroll
    for (int k = 0; k < 8; ++k) {
      if (idx[k] < CAP) edges[((size_t)dv[k] << 5) + idx[k]] = rec[k];
    }
  } else {
    for (int k = 0; k < 8 && e0 + k < E; ++k) {
      int e = e0 + k;
      int d = dst[e];
      int idx = atomicAdd(&cursor[d], 1);
      if (idx < CAP) {
        unsigned int q = (unsigned int)fminf(w[e] * 32768.0f, 32767.0f);
        edges[((size_t)d << 5) + idx] = (unsigned int)src[e] | (q << 17);
      }
    }
  }
}

// ---- neigh gather: one wave/row, 2 edges per iter (half-wave each) ---------
__global__ __launch_bounds__(256) void gather_kernel(
    const unsigned int* __restrict__ xmbf, const unsigned int* __restrict__ edges,
    const int* __restrict__ cursor, unsigned int* __restrict__ neighbf,
    float* __restrict__ sumw, int NA) {
  int wave = threadIdx.x >> 6, lane = threadIdx.x & 63;
  int a = blockIdx.x * 4 + wave;
  if (a >= NA) return;
  int half = lane >> 5;   // which edge of the pair this half-wave takes
  int fp = lane & 31;     // feature-pair index: feats (2fp, 2fp+1)
  int cnt = cursor[a];
  if (cnt > CAP) cnt = CAP;
  const unsigned int* eb = edges + ((size_t)a << 5);
  float accx = 0.f, accy = 0.f, ws = 0.f;
  const float wscale = 1.0f / 32768.0f;
  for (int e0 = 0; e0 < cnt; e0 += 8) {
#pragma unroll
    for (int k = 0; k < 4; ++k) {
      int e = e0 + k * 2 + half;
      bool valid = e < cnt;
      unsigned int p = eb[valid ? e : 0];
      float w = valid ? (float)(p >> 17) * wscale : 0.f;
      unsigned int s = p & 0x1ffffu;
      unsigned int xp = xmbf[(size_t)s * 32 + fp];
      float x0 = __uint_as_float(xp << 16);            // feat 2fp
      float x1 = __uint_as_float(xp & 0xffff0000u);    // feat 2fp+1
      accx += w * x0;
      accy += w * x1;
      ws += w;
    }
  }
  accx += __shfl_xor(accx, 32, 64);
  accy += __shfl_xor(accy, 32, 64);
  ws   += __shfl_xor(ws, 32, 64);
  if (half == 0) {
    neighbf[(size_t)a * 32 + fp] = pk_bf16(accx, accy);
    if (fp == 0) sumw[a] = ws;
  }
}

// ---- fused account GEMM + head: 512 threads, 256 rows/block ----------------
__global__ __launch_bounds__(512) void acct_kernel(
    const float* __restrict__ xa, const unsigned int* __restrict__ neighbf,
    const float* __restrict__ sumw, const unsigned int* __restrict__ Wcomb32,
    const float* __restrict__ beff, const float* __restrict__ vbr,
    const float* __restrict__ Wo, const float* __restrict__ bo,
    float* __restrict__ out, int NA) {
  __shared__ unsigned int B_lds[24 * 128 * 4];   // 48 KB
  int tid = threadIdx.x;
#pragma unroll
  for (int it = 0; it < 6; ++it) {
    int i = tid + it * 512;
    int c = i >> 7, col = i & 127;
    uint4 v = ((const uint4*)Wcomb32)[col * 24 + c];
    *((uint4*)&B_lds[i * 4]) = v;
  }
  __syncthreads();

  int wave = tid >> 6, lane = tid & 63;
  int n15 = lane & 15, quad = lane >> 4;
  float bo0 = bo[0];

  union U4 { uint4 u; short8 h; };

#pragma unroll
  for (int tile = 0; tile < 2; ++tile) {
    int rowbase = blockIdx.x * 256 + (wave * 2 + tile) * 16;
    int m = rowbase + n15;
    int mc = min(m, NA - 1);

    U4 afr[6];
    const float* xrow = xa + (size_t)mc * 128 + quad * 8;
#pragma unroll
    for (int s = 0; s < 4; ++s) {
      float4 f0 = ((const float4*)(xrow + s * 32))[0];
      float4 f1 = ((const float4*)(xrow + s * 32))[1];
      afr[s].u = make_uint4(pk_bf16(f0.x, f0.y), pk_bf16(f0.z, f0.w),
                            pk_bf16(f1.x, f1.y), pk_bf16(f1.z, f1.w));
    }
#pragma unroll
    for (int s = 0; s < 2; ++s) {
      afr[4 + s].u = ((const uint4*)(neighbf + (size_t)mc * 32))[s * 4 + quad];
    }

    f32x4 acc[8];
#pragma unroll
    for (int t = 0; t < 8; ++t) acc[t] = (f32x4){0.f, 0.f, 0.f, 0.f};

#pragma unroll
    for (int s = 0; s < 6; ++s) {
#pragma unroll
      for (int t = 0; t < 8; ++t) {
        U4 bfr;
        bfr.u = *((const uint4*)&B_lds[((s * 4 + quad) * 128 + t * 16 + n15) * 4]);
        acc[t] = __builtin_amdgcn_mfma_f32_16x16x32_bf16(afr[s].h, bfr.h, acc[t], 0, 0, 0);
      }
    }

    float sw[4];
#pragma unroll
    for (int r = 0; r < 4; ++r) {
      int grow = rowbase + quad * 4 + r;
      sw[r] = (grow < NA) ? sumw[grow] : 0.f;
    }
    float rowsum[4] = {0.f, 0.f, 0.f, 0.f};
#pragma unroll
    for (int t = 0; t < 8; ++t) {
      int col = t * 16 + n15;
      float be = beff[col], vb = vbr[col], wo = Wo[col];
#pragma unroll
      for (int r = 0; r < 4; ++r) {
        float h = acc[t][r] + be + sw[r] * vb;
        h = fmaxf(h, 0.f);
        rowsum[r] += h * wo;
      }
    }
#pragma unroll
    for (int msk = 1; msk <= 8; msk <<= 1) {
#pragma unroll
      for (int r = 0; r < 4; ++r) rowsum[r] += __shfl_xor(rowsum[r], msk, 64);
    }
    if (n15 == 0) {
#pragma unroll
      for (int r = 0; r < 4; ++r) {
        int grow = rowbase + quad * 4 + r;
        if (grow < NA) out[grow] = 1.0f / (1.0f + __expf(-(rowsum[r] + bo0)));
      }
    }
  }
}

extern "C" void kernel_launch(void* const* d_in, const int* in_sizes, int n_in,
                              void* d_out, int out_size, void* d_ws, size_t ws_size,
                              hipStream_t stream) {
  const float* xa      = (const float*)d_in[0];
  const float* xm      = (const float*)d_in[1];
  const int*   ema_src = (const int*)d_in[5];
  const int*   ema_dst = (const int*)d_in[6];
  const float* ema_w   = (const float*)d_in[7];
  const float* Wp_a    = (const float*)d_in[8];
  const float* bp_a    = (const float*)d_in[9];
  const float* Wr_ma   = (const float*)d_in[14];
  const float* br_ma   = (const float*)d_in[15];
  const float* Wc_a    = (const float*)d_in[16];
  const float* bc_a    = (const float*)d_in[17];
  const float* Wo      = (const float*)d_in[20];
  const float* bo      = (const float*)d_in[21];

  int NA = in_sizes[0] / 128;
  int NM = in_sizes[1] / 64;
  int E  = in_sizes[5];

  char* ws = (char*)d_ws;
  size_t off = 0;
  auto take = [&](size_t bytes) { char* p = ws + off; off = (off + bytes + 255) & ~(size_t)255; return p; };
  unsigned int* neighbf = (unsigned int*)take((size_t)NA * 32 * 4);      // bf16 pairs [NA][32]
  unsigned int* xmbf    = (unsigned int*)take((size_t)NM * 32 * 4);      // bf16 pairs [NM][32]
  float* sumw           = (float*)take((size_t)NA * 4);
  int* cursor           = (int*)take((size_t)NA * 4);
  unsigned int* edges   = (unsigned int*)take((size_t)NA * CAP * 4);     // capacity-32 buckets
  unsigned short* Wcomb = (unsigned short*)take(128 * 192 * 2);
  float* beff           = (float*)take(128 * 4);
  float* vbr            = (float*)take(128 * 4);

  hipMemsetAsync(cursor, 0, (size_t)NA * 4, stream);

  int nq = NM * 16;                       // float4 groups in x_merchant
  int nb_cvt = (nq + 255) / 256;
  int nb_sc  = (E + 2047) / 2048;         // single-pass, 8 edges/thread
  setup_kernel<<<128 + nb_cvt + nb_sc, 256, 0, stream>>>(
      xm, xmbf, nq, ema_src, ema_dst, ema_w, cursor, edges, E,
      Wp_a, bp_a, Wr_ma, br_ma, Wc_a, bc_a, Wcomb, beff, vbr, nb_cvt);

  int gb = (NA + 3) / 4;
  gather_kernel<<<gb, 256, 0, stream>>>(xmbf, edges, cursor, neighbf, sumw, NA);

  int ab = (NA + 255) / 256;
  acct_kernel<<<ab, 512, 0, stream>>>(xa, neighbf, sumw, (const unsigned int*)Wcomb,
                                      beff, vbr, Wo, bo, (float*)d_out, NA);
}

// Round 7
// 340.530 us; speedup vs baseline: 1.0676x; 1.0676x over previous
//
#include <hip/hip_runtime.h>

// HeteroGraphSage on MI355X — round 17: revert to 8-way XCD-partitioned
// scatter (R16 proved atomics NEED XCD-locality: unpartitioned = +26us from
// cursor-line migration across L2s) + 16 edges/thread ILP (R12 lesson, one
// more doubling). acct stays 512-thr (R14). Speculative vec loads kept (R13).
// Pipeline: memset(cursor) -> [prep|cvt|scatter] -> gather -> acct.
//   neigh64[a] = sum_e w_e * x_m[src_e] ; sumw[a] = sum_e w_e
//   h_a = relu( Wcomb @ [x_a | neigh64] + sumw*vbr + beff )
//   out = sigmoid(Wo . h_a + bo)
// Lessons: R7 — edge phases need huge TLP; R8/R9/R16 — cursor atomics need
// XCD partition (b&7), worth >=26us; R10 — harness fill ~60us fixed; R11 —
// capacity-32 buckets == exact CSR (Poisson(5)); R12 — ILP-batch edges;
// R13 — scatter not read-latency bound; R14 — acct 512-thr occupancy fix;
// R15 — NT streaming neutral on gfx950; R16 — single-pass scatter disaster.
// Pre-commit: if setup >=66us here, scatter is at its structural floor
// (~2M scattered L2 ops); stop tuning it.

typedef __attribute__((ext_vector_type(8))) short short8;
typedef __attribute__((ext_vector_type(4))) float f32x4;

#define PSH 12   // accounts-per-chunk shift for XCD partitioning (4096)
#define CAP 32   // bucket capacity (max observed degree ~19; P(>=32) ~ 1e-15/row)

__device__ inline unsigned short f32_bf16(float f) {
  unsigned int u = __float_as_uint(f);
  u += 0x7FFF + ((u >> 16) & 1);   // round-to-nearest-even
  return (unsigned short)(u >> 16);
}
__device__ inline unsigned int pk_bf16(float a, float b) {
  return (unsigned int)f32_bf16(a) | ((unsigned int)f32_bf16(b) << 16);
}

// ---- merged front-end: [prep | cvt_xm | scatter] by blockIdx range ---------
// record: [wq:15b << 17 | src:17b]; w in [0,1) -> q=w*32768, err <= 3e-5.
__global__ __launch_bounds__(256) void setup_kernel(
    const float* __restrict__ xm, unsigned int* __restrict__ xmbf, int nq,
    const int* __restrict__ src, const int* __restrict__ dst,
    const float* __restrict__ w, int* __restrict__ cursor,
    unsigned int* __restrict__ edges, int E,
    const float* __restrict__ Wp_a, const float* __restrict__ bp_a,
    const float* __restrict__ Wr_ma, const float* __restrict__ br_ma,
    const float* __restrict__ Wc_a, const float* __restrict__ bc_a,
    unsigned short* __restrict__ Wcomb, float* __restrict__ beff,
    float* __restrict__ vbr, int nb_cvt) {
  __shared__ float wc_s[256];
  int b = blockIdx.x;
  int t = threadIdx.x;
  if (b < 128) {
    // ---- prep: fold Wc_a @ [Wp_a ; Wr_ma] into Wcomb[128][192] bf16 -------
    int col = b;
    wc_s[t] = Wc_a[col * 256 + t];
    __syncthreads();
    int wave = t >> 6, lane = t & 63;
    if (wave < 2) {
      int k = t;   // 0..127
      float acc = 0.f;
#pragma unroll
      for (int j = 0; j < 128; j += 4) {
        float a0 = Wp_a[(j + 0) * 128 + k];
        float a1 = Wp_a[(j + 1) * 128 + k];
        float a2 = Wp_a[(j + 2) * 128 + k];
        float a3 = Wp_a[(j + 3) * 128 + k];
        acc += wc_s[j] * a0 + wc_s[j + 1] * a1 + wc_s[j + 2] * a2 + wc_s[j + 3] * a3;
      }
      Wcomb[col * 192 + k] = f32_bf16(acc);
    } else if (wave == 2) {
      int kk = lane;   // 0..63
      float acc = 0.f;
#pragma unroll
      for (int j = 0; j < 128; j += 4) {
        float a0 = Wr_ma[(j + 0) * 64 + kk];
        float a1 = Wr_ma[(j + 1) * 64 + kk];
        float a2 = Wr_ma[(j + 2) * 64 + kk];
        float a3 = Wr_ma[(j + 3) * 64 + kk];
        acc += wc_s[128 + j] * a0 + wc_s[129 + j] * a1 + wc_s[130 + j] * a2 + wc_s[131 + j] * a3;
      }
      Wcomb[col * 192 + 128 + kk] = f32_bf16(acc);
    } else {
      float v1 = wc_s[lane] * bp_a[lane] + wc_s[lane + 64] * bp_a[lane + 64];
      float v2 = wc_s[128 + lane] * br_ma[lane] + wc_s[192 + lane] * br_ma[lane + 64];
#pragma unroll
      for (int m = 1; m <= 32; m <<= 1) {
        v1 += __shfl_xor(v1, m, 64);
        v2 += __shfl_xor(v2, m, 64);
      }
      if (lane == 0) { beff[col] = v1 + bc_a[col]; vbr[col] = v2; }
    }
    return;
  }
  b -= 128;
  if (b < nb_cvt) {
    // ---- cvt: x_merchant f32 -> packed bf16 pairs, float4-vectorized ------
    int i = b * 256 + t;
    if (i < nq) {
      float4 v = ((const float4*)xm)[i];
      ((uint2*)xmbf)[i] = make_uint2(pk_bf16(v.x, v.y), pk_bf16(v.z, v.w));
    }
    return;
  }
  b -= nb_cvt;
  // ---- scatter: XCD-partitioned, 16 edges/thread, speculative vec loads --
  int slice = b >> 3;
  int p = b & 7;
  int e0 = slice * 4096 + t * 16;
  if (e0 >= E) return;
  if (e0 + 16 <= E) {
    int dv[16], sv[16];
    float wv[16];
#pragma unroll
    for (int q = 0; q < 4; ++q) {
      int4 dq = ((const int4*)(dst + e0))[q];
      int4 sq = ((const int4*)(src + e0))[q];
      float4 wq = ((const float4*)(w + e0))[q];
      dv[q * 4 + 0] = dq.x; dv[q * 4 + 1] = dq.y; dv[q * 4 + 2] = dq.z; dv[q * 4 + 3] = dq.w;
      sv[q * 4 + 0] = sq.x; sv[q * 4 + 1] = sq.y; sv[q * 4 + 2] = sq.z; sv[q * 4 + 3] = sq.w;
      wv[q * 4 + 0] = wq.x; wv[q * 4 + 1] = wq.y; wv[q * 4 + 2] = wq.z; wv[q * 4 + 3] = wq.w;
    }
    unsigned int rec[16];
#pragma unroll
    for (int k = 0; k < 16; ++k) {
      unsigned int q = (unsigned int)fminf(wv[k] * 32768.0f, 32767.0f);
      rec[k] = (unsigned int)sv[k] | (q << 17);
    }
#pragma unroll
    for (int k = 0; k < 16; ++k) {
      int d = dv[k];
      if (((d >> PSH) & 7) != p) continue;
      int idx = atomicAdd(&cursor[d], 1);
      if (idx < CAP) edges[((size_t)d << 5) + idx] = rec[k];
    }
  } else {
    for (int k = 0; k < 16 && e0 + k < E; ++k) {
      int e = e0 + k;
      int d = dst[e];
      if (((d >> PSH) & 7) != p) continue;
      int idx = atomicAdd(&cursor[d], 1);
      if (idx < CAP) {
        unsigned int q = (unsigned int)fminf(w[e] * 32768.0f, 32767.0f);
        edges[((size_t)d << 5) + idx] = (unsigned int)src[e] | (q << 17);
      }
    }
  }
}

// ---- neigh gather: one wave/row, 2 edges per iter (half-wave each) ---------
__global__ __launch_bounds__(256) void gather_kernel(
    const unsigned int* __restrict__ xmbf, const unsigned int* __restrict__ edges,
    const int* __restrict__ cursor, unsigned int* __restrict__ neighbf,
    float* __restrict__ sumw, int NA) {
  int wave = threadIdx.x >> 6, lane = threadIdx.x & 63;
  int a = blockIdx.x * 4 + wave;
  if (a >= NA) return;
  int half = lane >> 5;   // which edge of the pair this half-wave takes
  int fp = lane & 31;     // feature-pair index: feats (2fp, 2fp+1)
  int cnt = cursor[a];
  if (cnt > CAP) cnt = CAP;
  const unsigned int* eb = edges + ((size_t)a << 5);
  float accx = 0.f, accy = 0.f, ws = 0.f;
  const float wscale = 1.0f / 32768.0f;
  for (int e0 = 0; e0 < cnt; e0 += 8) {
#pragma unroll
    for (int k = 0; k < 4; ++k) {
      int e = e0 + k * 2 + half;
      bool valid = e < cnt;
      unsigned int p = eb[valid ? e : 0];
      float w = valid ? (float)(p >> 17) * wscale : 0.f;
      unsigned int s = p & 0x1ffffu;
      unsigned int xp = xmbf[(size_t)s * 32 + fp];
      float x0 = __uint_as_float(xp << 16);            // feat 2fp
      float x1 = __uint_as_float(xp & 0xffff0000u);    // feat 2fp+1
      accx += w * x0;
      accy += w * x1;
      ws += w;
    }
  }
  accx += __shfl_xor(accx, 32, 64);
  accy += __shfl_xor(accy, 32, 64);
  ws   += __shfl_xor(ws, 32, 64);
  if (half == 0) {
    neighbf[(size_t)a * 32 + fp] = pk_bf16(accx, accy);
    if (fp == 0) sumw[a] = ws;
  }
}

// ---- fused account GEMM + head: 512 threads, 256 rows/block ----------------
__global__ __launch_bounds__(512) void acct_kernel(
    const float* __restrict__ xa, const unsigned int* __restrict__ neighbf,
    const float* __restrict__ sumw, const unsigned int* __restrict__ Wcomb32,
    const float* __restrict__ beff, const float* __restrict__ vbr,
    const float* __restrict__ Wo, const float* __restrict__ bo,
    float* __restrict__ out, int NA) {
  __shared__ unsigned int B_lds[24 * 128 * 4];   // 48 KB
  int tid = threadIdx.x;
#pragma unroll
  for (int it = 0; it < 6; ++it) {
    int i = tid + it * 512;
    int c = i >> 7, col = i & 127;
    uint4 v = ((const uint4*)Wcomb32)[col * 24 + c];
    *((uint4*)&B_lds[i * 4]) = v;
  }
  __syncthreads();

  int wave = tid >> 6, lane = tid & 63;
  int n15 = lane & 15, quad = lane >> 4;
  float bo0 = bo[0];

  union U4 { uint4 u; short8 h; };

#pragma unroll
  for (int tile = 0; tile < 2; ++tile) {
    int rowbase = blockIdx.x * 256 + (wave * 2 + tile) * 16;
    int m = rowbase + n15;
    int mc = min(m, NA - 1);

    U4 afr[6];
    const float* xrow = xa + (size_t)mc * 128 + quad * 8;
#pragma unroll
    for (int s = 0; s < 4; ++s) {
      float4 f0 = ((const float4*)(xrow + s * 32))[0];
      float4 f1 = ((const float4*)(xrow + s * 32))[1];
      afr[s].u = make_uint4(pk_bf16(f0.x, f0.y), pk_bf16(f0.z, f0.w),
                            pk_bf16(f1.x, f1.y), pk_bf16(f1.z, f1.w));
    }
#pragma unroll
    for (int s = 0; s < 2; ++s) {
      afr[4 + s].u = ((const uint4*)(neighbf + (size_t)mc * 32))[s * 4 + quad];
    }

    f32x4 acc[8];
#pragma unroll
    for (int t = 0; t < 8; ++t) acc[t] = (f32x4){0.f, 0.f, 0.f, 0.f};

#pragma unroll
    for (int s = 0; s < 6; ++s) {
#pragma unroll
      for (int t = 0; t < 8; ++t) {
        U4 bfr;
        bfr.u = *((const uint4*)&B_lds[((s * 4 + quad) * 128 + t * 16 + n15) * 4]);
        acc[t] = __builtin_amdgcn_mfma_f32_16x16x32_bf16(afr[s].h, bfr.h, acc[t], 0, 0, 0);
      }
    }

    float sw[4];
#pragma unroll
    for (int r = 0; r < 4; ++r) {
      int grow = rowbase + quad * 4 + r;
      sw[r] = (grow < NA) ? sumw[grow] : 0.f;
    }
    float rowsum[4] = {0.f, 0.f, 0.f, 0.f};
#pragma unroll
    for (int t = 0; t < 8; ++t) {
      int col = t * 16 + n15;
      float be = beff[col], vb = vbr[col], wo = Wo[col];
#pragma unroll
      for (int r = 0; r < 4; ++r) {
        float h = acc[t][r] + be + sw[r] * vb;
        h = fmaxf(h, 0.f);
        rowsum[r] += h * wo;
      }
    }
#pragma unroll
    for (int msk = 1; msk <= 8; msk <<= 1) {
#pragma unroll
      for (int r = 0; r < 4; ++r) rowsum[r] += __shfl_xor(rowsum[r], msk, 64);
    }
    if (n15 == 0) {
#pragma unroll
      for (int r = 0; r < 4; ++r) {
        int grow = rowbase + quad * 4 + r;
        if (grow < NA) out[grow] = 1.0f / (1.0f + __expf(-(rowsum[r] + bo0)));
      }
    }
  }
}

extern "C" void kernel_launch(void* const* d_in, const int* in_sizes, int n_in,
                              void* d_out, int out_size, void* d_ws, size_t ws_size,
                              hipStream_t stream) {
  const float* xa      = (const float*)d_in[0];
  const float* xm      = (const float*)d_in[1];
  const int*   ema_src = (const int*)d_in[5];
  const int*   ema_dst = (const int*)d_in[6];
  const float* ema_w   = (const float*)d_in[7];
  const float* Wp_a    = (const float*)d_in[8];
  const float* bp_a    = (const float*)d_in[9];
  const float* Wr_ma   = (const float*)d_in[14];
  const float* br_ma   = (const float*)d_in[15];
  const float* Wc_a    = (const float*)d_in[16];
  const float* bc_a    = (const float*)d_in[17];
  const float* Wo      = (const float*)d_in[20];
  const float* bo      = (const float*)d_in[21];

  int NA = in_sizes[0] / 128;
  int NM = in_sizes[1] / 64;
  int E  = in_sizes[5];

  char* ws = (char*)d_ws;
  size_t off = 0;
  auto take = [&](size_t bytes) { char* p = ws + off; off = (off + bytes + 255) & ~(size_t)255; return p; };
  unsigned int* neighbf = (unsigned int*)take((size_t)NA * 32 * 4);      // bf16 pairs [NA][32]
  unsigned int* xmbf    = (unsigned int*)take((size_t)NM * 32 * 4);      // bf16 pairs [NM][32]
  float* sumw           = (float*)take((size_t)NA * 4);
  int* cursor           = (int*)take((size_t)NA * 4);
  unsigned int* edges   = (unsigned int*)take((size_t)NA * CAP * 4);     // capacity-32 buckets
  unsigned short* Wcomb = (unsigned short*)take(128 * 192 * 2);
  float* beff           = (float*)take(128 * 4);
  float* vbr            = (float*)take(128 * 4);

  hipMemsetAsync(cursor, 0, (size_t)NA * 4, stream);

  int nq = NM * 16;                       // float4 groups in x_merchant
  int nb_cvt = (nq + 255) / 256;
  int nb_sc  = ((E + 4095) / 4096) * 8;   // 16 edges/thread, 8-way partitioned
  setup_kernel<<<128 + nb_cvt + nb_sc, 256, 0, stream>>>(
      xm, xmbf, nq, ema_src, ema_dst, ema_w, cursor, edges, E,
      Wp_a, bp_a, Wr_ma, br_ma, Wc_a, bc_a, Wcomb, beff, vbr, nb_cvt);

  int gb = (NA + 3) / 4;
  gather_kernel<<<gb, 256, 0, stream>>>(xmbf, edges, cursor, neighbf, sumw, NA);

  int ab = (NA + 255) / 256;
  acct_kernel<<<ab, 512, 0, stream>>>(xa, neighbf, sumw, (const unsigned int*)Wcomb,
                                      beff, vbr, Wo, bo, (float*)d_out, NA);
}

// Round 8
// 317.443 us; speedup vs baseline: 1.1452x; 1.0727x over previous
//
#include <hip/hip_runtime.h>

// HeteroGraphSage on MI355X — round 18: gather fused into acct. R17 pre-commit
// fired (setup ~68us at its structural floor: scattered atomics+stores). The
// gather kernel's only products were neighbf (25.6MB write + 25.6MB re-read)
// and sumw — pure intermediate traffic + a dispatch ramp. acct's wave layout
// absorbs it: for row n15, quad-lanes split the 64 merchant feats exactly on
// MFMA A-fragment boundaries (uint4 #quad, #quad+4 per edge row — zero
// duplication), f32 accumulate, pack afr[4..5] in regs, sumw via __shfl.
// Pipeline: memset(cursor) -> [prep|cvt|scatter] -> acct. 3 dispatches.
//   neigh64[a] = sum_e w_e * x_m[src_e] ; sumw[a] = sum_e w_e
//   h_a = relu( Wcomb @ [x_a | neigh64] + sumw*vbr + beff )
//   out = sigmoid(Wo . h_a + bo)
// Lessons: R8/R9/R16 — cursor atomics need XCD partition (worth >=26us);
// R10 — harness fill ~60us fixed; R11 — capacity-32 buckets == exact CSR
// (Poisson(5)); R12 — ILP-batch edges; R14 — acct 512-thr occupancy; R15 —
// NT streaming neutral; R17 — scatter at structural floor, stop tuning.
// Pre-commit: if total >= 335, fusion is a wash -> revert to R13 form.

typedef __attribute__((ext_vector_type(8))) short short8;
typedef __attribute__((ext_vector_type(4))) float f32x4;

#define PSH 12   // accounts-per-chunk shift for XCD partitioning (4096)
#define CAP 32   // bucket capacity (max observed degree ~19; P(>=32) ~ 1e-15/row)

__device__ inline unsigned short f32_bf16(float f) {
  unsigned int u = __float_as_uint(f);
  u += 0x7FFF + ((u >> 16) & 1);   // round-to-nearest-even
  return (unsigned short)(u >> 16);
}
__device__ inline unsigned int pk_bf16(float a, float b) {
  return (unsigned int)f32_bf16(a) | ((unsigned int)f32_bf16(b) << 16);
}
__device__ inline void fma8(float wE, uint4 v, float* a) {
  a[0] += wE * __uint_as_float(v.x << 16);
  a[1] += wE * __uint_as_float(v.x & 0xffff0000u);
  a[2] += wE * __uint_as_float(v.y << 16);
  a[3] += wE * __uint_as_float(v.y & 0xffff0000u);
  a[4] += wE * __uint_as_float(v.z << 16);
  a[5] += wE * __uint_as_float(v.z & 0xffff0000u);
  a[6] += wE * __uint_as_float(v.w << 16);
  a[7] += wE * __uint_as_float(v.w & 0xffff0000u);
}

// ---- merged front-end: [prep | cvt_xm | scatter] by blockIdx range ---------
// record: [wq:15b << 17 | src:17b]; w in [0,1) -> q=w*32768, err <= 3e-5.
__global__ __launch_bounds__(256) void setup_kernel(
    const float* __restrict__ xm, unsigned int* __restrict__ xmbf, int nq,
    const int* __restrict__ src, const int* __restrict__ dst,
    const float* __restrict__ w, int* __restrict__ cursor,
    unsigned int* __restrict__ edges, int E,
    const float* __restrict__ Wp_a, const float* __restrict__ bp_a,
    const float* __restrict__ Wr_ma, const float* __restrict__ br_ma,
    const float* __restrict__ Wc_a, const float* __restrict__ bc_a,
    unsigned short* __restrict__ Wcomb, float* __restrict__ beff,
    float* __restrict__ vbr, int nb_cvt) {
  __shared__ float wc_s[256];
  int b = blockIdx.x;
  int t = threadIdx.x;
  if (b < 128) {
    // ---- prep: fold Wc_a @ [Wp_a ; Wr_ma] into Wcomb[128][192] bf16 -------
    int col = b;
    wc_s[t] = Wc_a[col * 256 + t];
    __syncthreads();
    int wave = t >> 6, lane = t & 63;
    if (wave < 2) {
      int k = t;   // 0..127
      float acc = 0.f;
#pragma unroll
      for (int j = 0; j < 128; j += 4) {
        float a0 = Wp_a[(j + 0) * 128 + k];
        float a1 = Wp_a[(j + 1) * 128 + k];
        float a2 = Wp_a[(j + 2) * 128 + k];
        float a3 = Wp_a[(j + 3) * 128 + k];
        acc += wc_s[j] * a0 + wc_s[j + 1] * a1 + wc_s[j + 2] * a2 + wc_s[j + 3] * a3;
      }
      Wcomb[col * 192 + k] = f32_bf16(acc);
    } else if (wave == 2) {
      int kk = lane;   // 0..63
      float acc = 0.f;
#pragma unroll
      for (int j = 0; j < 128; j += 4) {
        float a0 = Wr_ma[(j + 0) * 64 + kk];
        float a1 = Wr_ma[(j + 1) * 64 + kk];
        float a2 = Wr_ma[(j + 2) * 64 + kk];
        float a3 = Wr_ma[(j + 3) * 64 + kk];
        acc += wc_s[128 + j] * a0 + wc_s[129 + j] * a1 + wc_s[130 + j] * a2 + wc_s[131 + j] * a3;
      }
      Wcomb[col * 192 + 128 + kk] = f32_bf16(acc);
    } else {
      float v1 = wc_s[lane] * bp_a[lane] + wc_s[lane + 64] * bp_a[lane + 64];
      float v2 = wc_s[128 + lane] * br_ma[lane] + wc_s[192 + lane] * br_ma[lane + 64];
#pragma unroll
      for (int m = 1; m <= 32; m <<= 1) {
        v1 += __shfl_xor(v1, m, 64);
        v2 += __shfl_xor(v2, m, 64);
      }
      if (lane == 0) { beff[col] = v1 + bc_a[col]; vbr[col] = v2; }
    }
    return;
  }
  b -= 128;
  if (b < nb_cvt) {
    // ---- cvt: x_merchant f32 -> packed bf16 pairs, float4-vectorized ------
    int i = b * 256 + t;
    if (i < nq) {
      float4 v = ((const float4*)xm)[i];
      ((uint2*)xmbf)[i] = make_uint2(pk_bf16(v.x, v.y), pk_bf16(v.z, v.w));
    }
    return;
  }
  b -= nb_cvt;
  // ---- scatter: XCD-partitioned, 16 edges/thread, speculative vec loads --
  int slice = b >> 3;
  int p = b & 7;
  int e0 = slice * 4096 + t * 16;
  if (e0 >= E) return;
  if (e0 + 16 <= E) {
    int dv[16], sv[16];
    float wv[16];
#pragma unroll
    for (int q = 0; q < 4; ++q) {
      int4 dq = ((const int4*)(dst + e0))[q];
      int4 sq = ((const int4*)(src + e0))[q];
      float4 wq = ((const float4*)(w + e0))[q];
      dv[q * 4 + 0] = dq.x; dv[q * 4 + 1] = dq.y; dv[q * 4 + 2] = dq.z; dv[q * 4 + 3] = dq.w;
      sv[q * 4 + 0] = sq.x; sv[q * 4 + 1] = sq.y; sv[q * 4 + 2] = sq.z; sv[q * 4 + 3] = sq.w;
      wv[q * 4 + 0] = wq.x; wv[q * 4 + 1] = wq.y; wv[q * 4 + 2] = wq.z; wv[q * 4 + 3] = wq.w;
    }
    unsigned int rec[16];
#pragma unroll
    for (int k = 0; k < 16; ++k) {
      unsigned int q = (unsigned int)fminf(wv[k] * 32768.0f, 32767.0f);
      rec[k] = (unsigned int)sv[k] | (q << 17);
    }
#pragma unroll
    for (int k = 0; k < 16; ++k) {
      int d = dv[k];
      if (((d >> PSH) & 7) != p) continue;
      int idx = atomicAdd(&cursor[d], 1);
      if (idx < CAP) edges[((size_t)d << 5) + idx] = rec[k];
    }
  } else {
    for (int k = 0; k < 16 && e0 + k < E; ++k) {
      int e = e0 + k;
      int d = dst[e];
      if (((d >> PSH) & 7) != p) continue;
      int idx = atomicAdd(&cursor[d], 1);
      if (idx < CAP) {
        unsigned int q = (unsigned int)fminf(w[e] * 32768.0f, 32767.0f);
        edges[((size_t)d << 5) + idx] = (unsigned int)src[e] | (q << 17);
      }
    }
  }
}

// ---- fused gather + account GEMM + head: 512 threads, 256 rows/block -------
__global__ __launch_bounds__(512) void acct_kernel(
    const float* __restrict__ xa, const unsigned int* __restrict__ xmbf,
    const unsigned int* __restrict__ edges, const int* __restrict__ cursor,
    const unsigned int* __restrict__ Wcomb32,
    const float* __restrict__ beff, const float* __restrict__ vbr,
    const float* __restrict__ Wo, const float* __restrict__ bo,
    float* __restrict__ out, int NA) {
  __shared__ unsigned int B_lds[24 * 128 * 4];   // 48 KB
  int tid = threadIdx.x;
#pragma unroll
  for (int it = 0; it < 6; ++it) {
    int i = tid + it * 512;
    int c = i >> 7, col = i & 127;
    uint4 v = ((const uint4*)Wcomb32)[col * 24 + c];
    *((uint4*)&B_lds[i * 4]) = v;
  }
  __syncthreads();

  int wave = tid >> 6, lane = tid & 63;
  int n15 = lane & 15, quad = lane >> 4;
  float bo0 = bo[0];
  const float wscale = 1.0f / 32768.0f;

  union U4 { uint4 u; short8 h; };

#pragma unroll
  for (int tile = 0; tile < 2; ++tile) {
    int rowbase = blockIdx.x * 256 + (wave * 2 + tile) * 16;
    int m = rowbase + n15;
    int mc = min(m, NA - 1);

    // ---- in-register gather for row mc: quad-lanes split 64 feats --------
    int cnt = min(cursor[mc], CAP);
    const unsigned int* eb = edges + ((size_t)mc << 5);
    uint4 r0 = ((const uint4*)eb)[0];
    uint4 r1 = ((const uint4*)eb)[1];
    unsigned int recs[8] = {r0.x, r0.y, r0.z, r0.w, r1.x, r1.y, r1.z, r1.w};
    float accA[8] = {0.f, 0.f, 0.f, 0.f, 0.f, 0.f, 0.f, 0.f};
    float accB[8] = {0.f, 0.f, 0.f, 0.f, 0.f, 0.f, 0.f, 0.f};
    float wsum = 0.f;
#pragma unroll
    for (int e = 0; e < 8; ++e) {
      if (e < cnt) {
        unsigned int pr = recs[e];
        float wE = (float)(pr >> 17) * wscale;
        const uint4* xr = (const uint4*)(xmbf + (size_t)(pr & 0x1ffffu) * 32);
        uint4 va = xr[quad];
        uint4 vb = xr[quad + 4];
        wsum += wE;
        fma8(wE, va, accA);
        fma8(wE, vb, accB);
      }
    }
    for (int e = 8; e < cnt; ++e) {   // rare Poisson tail (P ~ 7%)
      unsigned int pr = eb[e];
      float wE = (float)(pr >> 17) * wscale;
      const uint4* xr = (const uint4*)(xmbf + (size_t)(pr & 0x1ffffu) * 32);
      uint4 va = xr[quad];
      uint4 vb = xr[quad + 4];
      wsum += wE;
      fma8(wE, va, accA);
      fma8(wE, vb, accB);
    }

    U4 afr[6];
    afr[4].u = make_uint4(pk_bf16(accA[0], accA[1]), pk_bf16(accA[2], accA[3]),
                          pk_bf16(accA[4], accA[5]), pk_bf16(accA[6], accA[7]));
    afr[5].u = make_uint4(pk_bf16(accB[0], accB[1]), pk_bf16(accB[2], accB[3]),
                          pk_bf16(accB[4], accB[5]), pk_bf16(accB[6], accB[7]));

    const float* xrow = xa + (size_t)mc * 128 + quad * 8;
#pragma unroll
    for (int s = 0; s < 4; ++s) {
      float4 f0 = ((const float4*)(xrow + s * 32))[0];
      float4 f1 = ((const float4*)(xrow + s * 32))[1];
      afr[s].u = make_uint4(pk_bf16(f0.x, f0.y), pk_bf16(f0.z, f0.w),
                            pk_bf16(f1.x, f1.y), pk_bf16(f1.z, f1.w));
    }

    f32x4 acc[8];
#pragma unroll
    for (int t = 0; t < 8; ++t) acc[t] = (f32x4){0.f, 0.f, 0.f, 0.f};

#pragma unroll
    for (int s = 0; s < 6; ++s) {
#pragma unroll
      for (int t = 0; t < 8; ++t) {
        U4 bfr;
        bfr.u = *((const uint4*)&B_lds[((s * 4 + quad) * 128 + t * 16 + n15) * 4]);
        acc[t] = __builtin_amdgcn_mfma_f32_16x16x32_bf16(afr[s].h, bfr.h, acc[t], 0, 0, 0);
      }
    }

    float sw[4];
#pragma unroll
    for (int r = 0; r < 4; ++r) sw[r] = __shfl(wsum, quad * 4 + r, 64);

    float rowsum[4] = {0.f, 0.f, 0.f, 0.f};
#pragma unroll
    for (int t = 0; t < 8; ++t) {
      int col = t * 16 + n15;
      float be = beff[col], vb = vbr[col], wo = Wo[col];
#pragma unroll
      for (int r = 0; r < 4; ++r) {
        float h = acc[t][r] + be + sw[r] * vb;
        h = fmaxf(h, 0.f);
        rowsum[r] += h * wo;
      }
    }
#pragma unroll
    for (int msk = 1; msk <= 8; msk <<= 1) {
#pragma unroll
      for (int r = 0; r < 4; ++r) rowsum[r] += __shfl_xor(rowsum[r], msk, 64);
    }
    if (n15 == 0) {
#pragma unroll
      for (int r = 0; r < 4; ++r) {
        int grow = rowbase + quad * 4 + r;
        if (grow < NA) out[grow] = 1.0f / (1.0f + __expf(-(rowsum[r] + bo0)));
      }
    }
  }
}

extern "C" void kernel_launch(void* const* d_in, const int* in_sizes, int n_in,
                              void* d_out, int out_size, void* d_ws, size_t ws_size,
                              hipStream_t stream) {
  const float* xa      = (const float*)d_in[0];
  const float* xm      = (const float*)d_in[1];
  const int*   ema_src = (const int*)d_in[5];
  const int*   ema_dst = (const int*)d_in[6];
  const float* ema_w   = (const float*)d_in[7];
  const float* Wp_a    = (const float*)d_in[8];
  const float* bp_a    = (const float*)d_in[9];
  const float* Wr_ma   = (const float*)d_in[14];
  const float* br_ma   = (const float*)d_in[15];
  const float* Wc_a    = (const float*)d_in[16];
  const float* bc_a    = (const float*)d_in[17];
  const float* Wo      = (const float*)d_in[20];
  const float* bo      = (const float*)d_in[21];

  int NA = in_sizes[0] / 128;
  int NM = in_sizes[1] / 64;
  int E  = in_sizes[5];

  char* ws = (char*)d_ws;
  size_t off = 0;
  auto take = [&](size_t bytes) { char* p = ws + off; off = (off + bytes + 255) & ~(size_t)255; return p; };
  unsigned int* xmbf    = (unsigned int*)take((size_t)NM * 32 * 4);      // bf16 pairs [NM][32]
  int* cursor           = (int*)take((size_t)NA * 4);
  unsigned int* edges   = (unsigned int*)take((size_t)NA * CAP * 4);     // capacity-32 buckets
  unsigned short* Wcomb = (unsigned short*)take(128 * 192 * 2);
  float* beff           = (float*)take(128 * 4);
  float* vbr            = (float*)take(128 * 4);

  hipMemsetAsync(cursor, 0, (size_t)NA * 4, stream);

  int nq = NM * 16;                       // float4 groups in x_merchant
  int nb_cvt = (nq + 255) / 256;
  int nb_sc  = ((E + 4095) / 4096) * 8;   // 16 edges/thread, 8-way partitioned
  setup_kernel<<<128 + nb_cvt + nb_sc, 256, 0, stream>>>(
      xm, xmbf, nq, ema_src, ema_dst, ema_w, cursor, edges, E,
      Wp_a, bp_a, Wr_ma, br_ma, Wc_a, bc_a, Wcomb, beff, vbr, nb_cvt);

  int ab = (NA + 255) / 256;
  acct_kernel<<<ab, 512, 0, stream>>>(xa, xmbf, edges, cursor,
                                      (const unsigned int*)Wcomb,
                                      beff, vbr, Wo, bo, (float*)d_out, NA);
}